// Round 3
// baseline (169.176 us; speedup 1.0000x reference)
//
#include <hip/hip_runtime.h>
#include <math.h>

#define NN   1024
#define DD   256
#define NCLS 10
#define FEPS 1e-12f

#define TI 64      // i rows per block
#define TJ 128     // j cols per block
#define DC 32      // d chunk staged in LDS (== per-block d-range)
#define DSPLIT 8   // d-range split across blocks
#define NBLK ((NN / TI) * (NN / TJ) * DSPLIT)   // 16*8*8 = 1024 -> 4 blocks/CU

// row-dependent quad swizzle (8 quads per 32-float row)
__device__ __forceinline__ int swq8(int r, int q) {
    return (q + r + (r >> 3)) & 7;
}

__global__ __launch_bounds__(256) void count_kernel(const long long* __restrict__ tgt,
                                                    int* __restrict__ counts) {
    __shared__ int c[NCLS];
    int tid = threadIdx.x;
    if (tid < NCLS) c[tid] = 0;
    __syncthreads();
    for (int k = tid; k < NN; k += 256) atomicAdd(&c[(int)tgt[k]], 1);
    __syncthreads();
    if (tid < NCLS) counts[tid] = c[tid];
}

__global__ __launch_bounds__(256, 4) void pair_kernel(
    const float* __restrict__ fm_s, const float* __restrict__ fm_t,
    const float* __restrict__ lv, const long long* __restrict__ tgt,
    const int* __restrict__ counts, float* __restrict__ partials)
{
    // (3*64 + 128) * 32 * 4B = 40 KB -> 4 blocks/CU (160 KB LDS)
    __shared__ float Al[TI * DC];
    __shared__ float Bl[TI * DC];
    __shared__ float Vl[TI * DC];
    __shared__ float Fl[TJ * DC];

    const int bid  = blockIdx.x;
    const int tile = bid >> 3;        // 0..127
    const int kd   = bid & 7;         // d-eighth
    const int i0   = (tile >> 3) * TI;
    const int j0   = (tile & 7) * TJ;
    const int doff = kd * DC;

    const int tid  = threadIdx.x;
    const int tx   = tid & 15;        // j-group: 8 cols each
    const int ty   = tid >> 4;        // i-group: 4 rows each
    const int lane = tid & 63;
    const int w    = tid >> 6;        // wave 0..3
    const int dl   = lane & 31;       // d within chunk
    const int rsub = lane >> 5;       // row-pair select
    const int ql   = dl >> 2;
    const int el   = dl & 3;

    float s1[4][8], s2[4][8];
#pragma unroll
    for (int a = 0; a < 4; ++a)
#pragma unroll
        for (int b = 0; b < 8; ++b) { s1[a][b] = 0.f; s2[a][b] = 0.f; }

    // ---- stage (single chunk: per-block d-range == DC) ----
#pragma unroll
    for (int rp = 0; rp < TJ / 8; ++rp) {
        const int r = rp * 8 + w * 2 + rsub;
        Fl[r * DC + swq8(r, ql) * 4 + el] = fm_t[(j0 + r) * DD + doff + dl];
    }
#pragma unroll
    for (int rp = 0; rp < TI / 8; ++rp) {
        const int r = rp * 8 + w * 2 + rsub;
        const int g = (i0 + r) * DD + doff + dl;
        const float fs = fm_s[g];
        const float l  = lv[g];
        const float iv = 1.0f / (2.0f * expf(l) + FEPS);
        const int  a   = r * DC + swq8(r, ql) * 4 + el;
        const float fsiv = fs * iv;
        Al[a] = fmaf(fsiv, fs, 0.5f * l);
        Bl[a] = -2.0f * fsiv;
        Vl[a] = iv;
    }
    __syncthreads();

    // ---- compute: 8 quad-steps over the 32-wide d chunk ----
#pragma unroll 1
    for (int dq = 0; dq < DC / 4; ++dq) {
        float4 fa[4], fb[4], fv[4];
#pragma unroll
        for (int r = 0; r < 4; ++r) {
            const int i = ty * 4 + r;
            const int o = i * DC + swq8(i, dq) * 4;
            fa[r] = *(const float4*)&Al[o];
            fb[r] = *(const float4*)&Bl[o];
            fv[r] = *(const float4*)&Vl[o];
        }
#pragma unroll
        for (int rj = 0; rj < 8; ++rj) {
            const int j = tx * 8 + rj;
            const float4 f = *(const float4*)&Fl[j * DC + swq8(j, dq) * 4];
            const float4 f2 = make_float4(f.x * f.x, f.y * f.y, f.z * f.z, f.w * f.w);
#pragma unroll
            for (int ri = 0; ri < 4; ++ri) {
                const float t0 = fmaf(f2.x, fv[ri].x, fmaf(fb[ri].x, f.x, fa[ri].x));
                const float t1 = fmaf(f2.y, fv[ri].y, fmaf(fb[ri].y, f.y, fa[ri].y));
                const float t2 = fmaf(f2.z, fv[ri].z, fmaf(fb[ri].z, f.z, fa[ri].z));
                const float t3 = fmaf(f2.w, fv[ri].w, fmaf(fb[ri].w, f.w, fa[ri].w));
                s1[ri][rj] += (t0 + t1) + (t2 + t3);
                s2[ri][rj] += (fabsf(t0) + fabsf(t1)) + (fabsf(t2) + fabsf(t3));
            }
        }
    }

    // ---- epilogue: masked, row-normalized weighting (linear -> d-split safe) ----
    float csum = 0.f;
#pragma unroll
    for (int ri = 0; ri < 4; ++ri) {
        const int ti  = (int)tgt[i0 + ty * 4 + ri];
        const int cnt = counts[ti];
        const float wp = 1.0f / (float)cnt;
        const float wn = 1.0f / (float)(NN - cnt);
#pragma unroll
        for (int rj = 0; rj < 8; ++rj) {
            const int tj = (int)tgt[j0 + tx * 8 + rj];
            const float lp = 0.5f * (s2[ri][rj] + s1[ri][rj]);
            const float ln = 0.5f * (s2[ri][rj] - s1[ri][rj]);
            csum += (ti == tj) ? lp * wp : ln * wn;
        }
    }

    // deterministic reduction: wave shuffle, then 4 wave results via LDS
#pragma unroll
    for (int off = 32; off > 0; off >>= 1) csum += __shfl_down(csum, off);
    __syncthreads();
    if (lane == 0) Al[w] = csum;
    __syncthreads();
    if (tid == 0) partials[bid] = (Al[0] + Al[1]) + (Al[2] + Al[3]);
}

__global__ __launch_bounds__(256) void finalize_kernel(const float* __restrict__ partials,
                                                       float* __restrict__ out) {
    __shared__ float red[256];
    const int tid = threadIdx.x;
    red[tid] = (partials[tid] + partials[tid + 256]) +
               (partials[tid + 512] + partials[tid + 768]);
    __syncthreads();
    for (int s = 128; s > 0; s >>= 1) {
        if (tid < s) red[tid] += red[tid + s];
        __syncthreads();
    }
    if (tid == 0) out[0] = red[0] * (1.0f / (float)NN);
}

extern "C" void kernel_launch(void* const* d_in, const int* in_sizes, int n_in,
                              void* d_out, int out_size, void* d_ws, size_t ws_size,
                              hipStream_t stream) {
    const float* fm_s    = (const float*)d_in[0];
    const float* fm_t    = (const float*)d_in[1];
    const float* lv      = (const float*)d_in[2];
    const long long* tgt = (const long long*)d_in[3];
    // fusion_true (d_in[4]) == 0 path implemented

    int*   counts   = (int*)d_ws;
    float* partials = (float*)((char*)d_ws + 64);

    hipLaunchKernelGGL(count_kernel, dim3(1), dim3(256), 0, stream, tgt, counts);
    hipLaunchKernelGGL(pair_kernel, dim3(NBLK), dim3(256), 0, stream,
                       fm_s, fm_t, lv, tgt, counts, partials);
    hipLaunchKernelGGL(finalize_kernel, dim3(1), dim3(256), 0, stream,
                       partials, (float*)d_out);
}

// Round 4
// 45.806 us; speedup vs baseline: 3.6933x; 3.6933x over previous
//
#include <hip/hip_runtime.h>
#include <math.h>

#define NN   1024
#define DD   256
#define NCLS 10
#define FEPS 1e-12f

#define TI 64      // i rows per block
#define TJ 128     // j cols per block
#define DC 32      // d chunk staged in LDS (== per-block d-range)
#define DSPLIT 8   // d-range split across blocks
#define NBLK ((NN / TI) * (NN / TJ) * DSPLIT)   // 16*8*8 = 1024 -> 4 blocks/CU

// row-dependent quad swizzle (8 quads per 32-float row)
__device__ __forceinline__ int swq8(int r, int q) {
    return (q + r + (r >> 3)) & 7;
}

__global__ __launch_bounds__(256) void count_kernel(const long long* __restrict__ tgt,
                                                    int* __restrict__ counts) {
    __shared__ int c[NCLS];
    int tid = threadIdx.x;
    if (tid < NCLS) c[tid] = 0;
    __syncthreads();
    for (int k = tid; k < NN; k += 256) atomicAdd(&c[(int)tgt[k]], 1);
    __syncthreads();
    if (tid < NCLS) counts[tid] = c[tid];
}

__global__ __launch_bounds__(256) void pair_kernel(
    const float* __restrict__ fm_s, const float* __restrict__ fm_t,
    const float* __restrict__ lv, const long long* __restrict__ tgt,
    const int* __restrict__ counts, float* __restrict__ partials)
{
    // (3*64 + 128) * 32 * 4B = 40 KB -> 4 blocks/CU (160 KB LDS)
    __shared__ float Al[TI * DC];
    __shared__ float Bl[TI * DC];
    __shared__ float Vl[TI * DC];
    __shared__ float Fl[TJ * DC];

    const int bid  = blockIdx.x;
    const int tile = bid >> 3;        // 0..127
    const int kd   = bid & 7;         // d-eighth
    const int i0   = (tile >> 3) * TI;
    const int j0   = (tile & 7) * TJ;
    const int doff = kd * DC;

    const int tid  = threadIdx.x;
    const int tx   = tid & 15;        // j-group: 8 cols each
    const int ty   = tid >> 4;        // i-group: 4 rows each
    const int lane = tid & 63;
    const int w    = tid >> 6;        // wave 0..3
    const int dl   = lane & 31;       // d within chunk
    const int rsub = lane >> 5;       // row-pair select
    const int ql   = dl >> 2;
    const int el   = dl & 3;

    float s1[4][8], s2[4][8];
#pragma unroll
    for (int a = 0; a < 4; ++a)
#pragma unroll
        for (int b = 0; b < 8; ++b) { s1[a][b] = 0.f; s2[a][b] = 0.f; }

    // ---- stage (single chunk: per-block d-range == DC) ----
#pragma unroll
    for (int rp = 0; rp < TJ / 8; ++rp) {
        const int r = rp * 8 + w * 2 + rsub;
        Fl[r * DC + swq8(r, ql) * 4 + el] = fm_t[(j0 + r) * DD + doff + dl];
    }
#pragma unroll
    for (int rp = 0; rp < TI / 8; ++rp) {
        const int r = rp * 8 + w * 2 + rsub;
        const int g = (i0 + r) * DD + doff + dl;
        const float fs = fm_s[g];
        const float l  = lv[g];
        const float iv = 1.0f / (2.0f * expf(l) + FEPS);
        const int  a   = r * DC + swq8(r, ql) * 4 + el;
        const float fsiv = fs * iv;
        Al[a] = fmaf(fsiv, fs, 0.5f * l);
        Bl[a] = -2.0f * fsiv;
        Vl[a] = iv;
    }
    __syncthreads();

    // ---- compute: 8 quad-steps over the 32-wide d chunk ----
#pragma unroll 1
    for (int dq = 0; dq < DC / 4; ++dq) {
        float4 fa[4], fb[4], fv[4];
#pragma unroll
        for (int r = 0; r < 4; ++r) {
            const int i = ty * 4 + r;
            const int o = i * DC + swq8(i, dq) * 4;
            fa[r] = *(const float4*)&Al[o];
            fb[r] = *(const float4*)&Bl[o];
            fv[r] = *(const float4*)&Vl[o];
        }
#pragma unroll
        for (int rj = 0; rj < 8; ++rj) {
            const int j = tx * 8 + rj;
            const float4 f = *(const float4*)&Fl[j * DC + swq8(j, dq) * 4];
            const float4 f2 = make_float4(f.x * f.x, f.y * f.y, f.z * f.z, f.w * f.w);
#pragma unroll
            for (int ri = 0; ri < 4; ++ri) {
                const float t0 = fmaf(f2.x, fv[ri].x, fmaf(fb[ri].x, f.x, fa[ri].x));
                const float t1 = fmaf(f2.y, fv[ri].y, fmaf(fb[ri].y, f.y, fa[ri].y));
                const float t2 = fmaf(f2.z, fv[ri].z, fmaf(fb[ri].z, f.z, fa[ri].z));
                const float t3 = fmaf(f2.w, fv[ri].w, fmaf(fb[ri].w, f.w, fa[ri].w));
                s1[ri][rj] += (t0 + t1) + (t2 + t3);
                s2[ri][rj] += (fabsf(t0) + fabsf(t1)) + (fabsf(t2) + fabsf(t3));
            }
        }
    }

    // ---- epilogue: masked, row-normalized weighting (linear -> d-split safe) ----
    float csum = 0.f;
#pragma unroll
    for (int ri = 0; ri < 4; ++ri) {
        const int ti  = (int)tgt[i0 + ty * 4 + ri];
        const int cnt = counts[ti];
        const float wp = 1.0f / (float)cnt;
        const float wn = 1.0f / (float)(NN - cnt);
#pragma unroll
        for (int rj = 0; rj < 8; ++rj) {
            const int tj = (int)tgt[j0 + tx * 8 + rj];
            const float lp = 0.5f * (s2[ri][rj] + s1[ri][rj]);
            const float ln = 0.5f * (s2[ri][rj] - s1[ri][rj]);
            csum += (ti == tj) ? lp * wp : ln * wn;
        }
    }

    // deterministic reduction: wave shuffle, then 4 wave results via LDS
#pragma unroll
    for (int off = 32; off > 0; off >>= 1) csum += __shfl_down(csum, off);
    __syncthreads();
    if (lane == 0) Al[w] = csum;
    __syncthreads();
    if (tid == 0) partials[bid] = (Al[0] + Al[1]) + (Al[2] + Al[3]);
}

__global__ __launch_bounds__(256) void finalize_kernel(const float* __restrict__ partials,
                                                       float* __restrict__ out) {
    __shared__ float red[256];
    const int tid = threadIdx.x;
    red[tid] = (partials[tid] + partials[tid + 256]) +
               (partials[tid + 512] + partials[tid + 768]);
    __syncthreads();
    for (int s = 128; s > 0; s >>= 1) {
        if (tid < s) red[tid] += red[tid + s];
        __syncthreads();
    }
    if (tid == 0) out[0] = red[0] * (1.0f / (float)NN);
}

extern "C" void kernel_launch(void* const* d_in, const int* in_sizes, int n_in,
                              void* d_out, int out_size, void* d_ws, size_t ws_size,
                              hipStream_t stream) {
    const float* fm_s    = (const float*)d_in[0];
    const float* fm_t    = (const float*)d_in[1];
    const float* lv      = (const float*)d_in[2];
    const long long* tgt = (const long long*)d_in[3];
    // fusion_true (d_in[4]) == 0 path implemented

    int*   counts   = (int*)d_ws;
    float* partials = (float*)((char*)d_ws + 64);

    hipLaunchKernelGGL(count_kernel, dim3(1), dim3(256), 0, stream, tgt, counts);
    hipLaunchKernelGGL(pair_kernel, dim3(NBLK), dim3(256), 0, stream,
                       fm_s, fm_t, lv, tgt, counts, partials);
    hipLaunchKernelGGL(finalize_kernel, dim3(1), dim3(256), 0, stream,
                       partials, (float*)d_out);
}

// Round 5
// 39.023 us; speedup vs baseline: 4.3353x; 1.1738x over previous
//
#include <hip/hip_runtime.h>
#include <math.h>

#define NN   1024
#define DD   256
#define NCLS 10

#define TI 64      // i rows per block
#define TJ 128     // j cols per block
#define DC 32      // d chunk per block (8 quads/row)
#define DSPLIT 8
#define NBLK ((NN / TI) * (NN / TJ) * DSPLIT)   // 1024

typedef float f32x2 __attribute__((ext_vector_type(2)));
typedef float f32x4 __attribute__((ext_vector_type(4)));

__global__ __launch_bounds__(256) void count_kernel(const long long* __restrict__ tgt,
                                                    int* __restrict__ counts) {
    __shared__ int c[NCLS];
    int tid = threadIdx.x;
    if (tid < NCLS) c[tid] = 0;
    __syncthreads();
    for (int k = tid; k < NN; k += 256) atomicAdd(&c[(int)tgt[k]], 1);
    __syncthreads();
    if (tid < NCLS) counts[tid] = c[tid];
}

// Placement: i-side row r, d-quad q -> physical quad (q + (r>>2)) & 7
//            j-side row r, d-quad q -> physical quad (q + (r>>3)) & 7
// Read step k: thread(ty) i-quad (k+ty)&7, thread(tx) j-quad (k+tx)&7 -> both hold d-quad k.
__global__ __launch_bounds__(256) void pair_kernel(
    const float* __restrict__ fm_s, const float* __restrict__ fm_t,
    const float* __restrict__ lv, const long long* __restrict__ tgt,
    const int* __restrict__ counts, float* __restrict__ partials)
{
    __shared__ float Al[TI * DC];   // 8 KB  : fs^2*iv + 0.5*lv
    __shared__ float Bl[TI * DC];   // 8 KB  : -2*fs*iv
    __shared__ float Vl[TI * DC];   // 8 KB  : iv
    __shared__ float Fl[TJ * DC];   // 16 KB : fm_t

    const int bid  = blockIdx.x;
    const int tile = bid >> 3;
    const int kd   = bid & 7;
    const int i0   = (tile >> 3) * TI;
    const int j0   = (tile & 7) * TJ;
    const int doff = kd * DC;

    const int tid  = threadIdx.x;
    const int tx   = tid & 15;       // j-group: 8 cols
    const int ty   = tid >> 4;       // i-group: 4 rows
    const int lane = tid & 63;
    const int w    = tid >> 6;

    // ---- staging (float4 loads, b128 LDS writes, swizzled placement) ----
    const int srow = tid >> 3;       // 0..31
    const int sq   = tid & 7;        // source d-quad
#pragma unroll
    for (int p = 0; p < 4; ++p) {    // teacher tile: 128 rows
        const int r = p * 32 + srow;
        f32x4 v = *(const f32x4*)&fm_t[(j0 + r) * DD + doff + sq * 4];
        const int phys = (sq + (r >> 3)) & 7;
        *(f32x4*)&Fl[r * DC + phys * 4] = v;
    }
#pragma unroll
    for (int p = 0; p < 2; ++p) {    // student side: 64 rows
        const int r = p * 32 + srow;
        const int g = (i0 + r) * DD + doff + sq * 4;
        f32x4 fs = *(const f32x4*)&fm_s[g];
        f32x4 l  = *(const f32x4*)&lv[g];
        f32x4 A, B, V;
#pragma unroll
        for (int e = 0; e < 4; ++e) {
            const float iv = 0.5f * __expf(-l[e]);   // 1/(2e^l+1e-12) to ~2e-6 rel
            const float fsiv = fs[e] * iv;
            A[e] = fmaf(fsiv, fs[e], 0.5f * l[e]);
            B[e] = -2.0f * fsiv;
            V[e] = iv;
        }
        const int phys = (sq + (r >> 2)) & 7;
        *(f32x4*)&Al[r * DC + phys * 4] = A;
        *(f32x4*)&Bl[r * DC + phys * 4] = B;
        *(f32x4*)&Vl[r * DC + phys * 4] = V;
    }

    // hoist epilogue metadata loads (overlap with LDS fill + compute)
    const int* tgt32 = (const int*)tgt;   // int64 low words, values 0..9
    int ti_r[4], tj_r[8];
    float wp_r[4], wn_r[4];
#pragma unroll
    for (int ri = 0; ri < 4; ++ri) {
        ti_r[ri] = tgt32[(i0 + ty * 4 + ri) * 2];
        const int cnt = counts[ti_r[ri]];
        wp_r[ri] = 1.0f / (float)cnt;
        wn_r[ri] = 1.0f / (float)(NN - cnt);
    }
#pragma unroll
    for (int rj = 0; rj < 8; ++rj) tj_r[rj] = tgt32[(j0 + tx * 8 + rj) * 2];

    __syncthreads();

    float s1[4][8], s2[4][8];
#pragma unroll
    for (int a = 0; a < 4; ++a)
#pragma unroll
        for (int b = 0; b < 8; ++b) { s1[a][b] = 0.f; s2[a][b] = 0.f; }

    // ---- main loop: 8 steps, d-quad k each; imm-offset b128 reads ----
#pragma unroll
    for (int k = 0; k < 8; ++k) {
        const int iq = ((k + ty) & 7) * 4;
        const f32x4* pa = (const f32x4*)&Al[ty * 128 + iq];  // +r*32 floats = idx r*8
        const f32x4* pb = (const f32x4*)&Bl[ty * 128 + iq];
        const f32x4* pv = (const f32x4*)&Vl[ty * 128 + iq];
        f32x4 fa[4], fb[4], fv[4];
#pragma unroll
        for (int r = 0; r < 4; ++r) {
            fa[r] = pa[r * 8];
            fb[r] = pb[r * 8];
            fv[r] = pv[r * 8];
        }
        const f32x4* pf = (const f32x4*)&Fl[tx * 256 + ((k + tx) & 7) * 4];
#pragma unroll
        for (int rj = 0; rj < 8; ++rj) {
            const f32x4 f = pf[rj * 8];
            const f32x2 f01 = f.lo, f23 = f.hi;
            const f32x2 g01 = f01 * f01, g23 = f23 * f23;
#pragma unroll
            for (int ri = 0; ri < 4; ++ri) {
                const f32x2 t01 = __builtin_elementwise_fma(g01, fv[ri].lo,
                                    __builtin_elementwise_fma(f01, fb[ri].lo, fa[ri].lo));
                const f32x2 t23 = __builtin_elementwise_fma(g23, fv[ri].hi,
                                    __builtin_elementwise_fma(f23, fb[ri].hi, fa[ri].hi));
                s1[ri][rj] += (t01.x + t01.y) + (t23.x + t23.y);
                s2[ri][rj] += (fabsf(t01.x) + fabsf(t01.y)) + (fabsf(t23.x) + fabsf(t23.y));
            }
        }
    }

    // ---- epilogue: masked, row-normalized weighting ----
    float csum = 0.f;
#pragma unroll
    for (int ri = 0; ri < 4; ++ri) {
#pragma unroll
        for (int rj = 0; rj < 8; ++rj) {
            const float lp = 0.5f * (s2[ri][rj] + s1[ri][rj]);
            const float ln = 0.5f * (s2[ri][rj] - s1[ri][rj]);
            csum += (ti_r[ri] == tj_r[rj]) ? lp * wp_r[ri] : ln * wn_r[ri];
        }
    }

#pragma unroll
    for (int off = 32; off > 0; off >>= 1) csum += __shfl_down(csum, off);
    __syncthreads();
    if (lane == 0) Al[w] = csum;
    __syncthreads();
    if (tid == 0) partials[bid] = (Al[0] + Al[1]) + (Al[2] + Al[3]);
}

__global__ __launch_bounds__(256) void finalize_kernel(const float* __restrict__ partials,
                                                       float* __restrict__ out) {
    __shared__ float red[256];
    const int tid = threadIdx.x;
    red[tid] = (partials[tid] + partials[tid + 256]) +
               (partials[tid + 512] + partials[tid + 768]);
    __syncthreads();
    for (int s = 128; s > 0; s >>= 1) {
        if (tid < s) red[tid] += red[tid + s];
        __syncthreads();
    }
    if (tid == 0) out[0] = red[0] * (1.0f / (float)NN);
}

extern "C" void kernel_launch(void* const* d_in, const int* in_sizes, int n_in,
                              void* d_out, int out_size, void* d_ws, size_t ws_size,
                              hipStream_t stream) {
    const float* fm_s    = (const float*)d_in[0];
    const float* fm_t    = (const float*)d_in[1];
    const float* lv      = (const float*)d_in[2];
    const long long* tgt = (const long long*)d_in[3];
    // fusion_true (d_in[4]) == 0 path implemented

    int*   counts   = (int*)d_ws;
    float* partials = (float*)((char*)d_ws + 64);

    hipLaunchKernelGGL(count_kernel, dim3(1), dim3(256), 0, stream, tgt, counts);
    hipLaunchKernelGGL(pair_kernel, dim3(NBLK), dim3(256), 0, stream,
                       fm_s, fm_t, lv, tgt, counts, partials);
    hipLaunchKernelGGL(finalize_kernel, dim3(1), dim3(256), 0, stream,
                       partials, (float*)d_out);
}